// Round 11
// baseline (166.209 us; speedup 1.0000x reference)
//
#include <hip/hip_runtime.h>
#include <math.h>

// ---------------------------------------------------------------------------
// MMModel bf16-MFMA implementation. B=4, L=64, DM=1024, H=16, DK=DV=64,
// D=1024, DI=4096, nm=3. Row convention: row = (i*B + b)*L + l  (768 rows).
// ---------------------------------------------------------------------------

#define NEGV (-1000000000.0f)

typedef float f32x4 __attribute__((ext_vector_type(4)));
typedef short short8 __attribute__((ext_vector_type(8)));
typedef unsigned short u16x8 __attribute__((ext_vector_type(8)));
typedef unsigned short u16x4 __attribute__((ext_vector_type(4)));

typedef __attribute__((address_space(1))) const void glob_cv;
typedef __attribute__((address_space(3))) void lds_v;

static __device__ __forceinline__ unsigned short f2bf(float f) {
  unsigned u = __builtin_bit_cast(unsigned, f);
  u += 0x7fffu + ((u >> 16) & 1u);
  return (unsigned short)(u >> 16);
}
static __device__ __forceinline__ float bf2f(unsigned short h) {
  return __builtin_bit_cast(float, ((unsigned)h) << 16);
}

// async global->LDS, 16B per lane (linear dest = base + lane*16).
static __device__ __forceinline__ void gload16(const unsigned short* g,
                                               unsigned short* l) {
  __builtin_amdgcn_global_load_lds((glob_cv*)g, (lds_v*)l, 16, 0, 0);
}

// ---------------- prep: concat inputs + weight transpose/cast ---------------
// blocks [0,768): concat X (f32 + bf16). blocks [768, 768+ts): wt jobs.
struct WtJob { const float* src; unsigned short* dst; int K, N, tstart; };
struct WtJobs { WtJob j[9]; };

__global__ __launch_bounds__(256) void prep(const float4* __restrict__ t,
                                            const float4* __restrict__ a,
                                            const float4* __restrict__ v,
                                            float4* __restrict__ Xf,
                                            u16x4* __restrict__ Xb,
                                            WtJobs jobs) {
  __shared__ float Ls[32][33];
  const int tid = threadIdx.x;
  if (blockIdx.x < 768) {
    int id = blockIdx.x * 256 + tid;  // 768*256 float4s
    int m = id >> 16;
    int off = id & 65535;
    const float4* s = (m == 0) ? t : (m == 1) ? a : v;
    float4 val = s[off];
    Xf[id] = val;
    u16x4 bb;
    bb.x = f2bf(val.x); bb.y = f2bf(val.y);
    bb.z = f2bf(val.z); bb.w = f2bf(val.w);
    Xb[id] = bb;
    return;
  }
  const int bx = blockIdx.x - 768;
  int ji = 0;
#pragma unroll
  for (int tj = 1; tj < 9; ++tj)
    if (bx >= jobs.j[tj].tstart) ji = tj;
  const WtJob jb = jobs.j[ji];
  int local = bx - jb.tstart;
  int ntx = jb.N >> 5;
  int tk = local / ntx, tn = local - tk * ntx;
  const int r = tid >> 3, c = (tid & 7) * 4;
  float4 vv = *(const float4*)(jb.src + (size_t)(tk * 32 + r) * jb.N + tn * 32 + c);
  Ls[r][c + 0] = vv.x; Ls[r][c + 1] = vv.y;
  Ls[r][c + 2] = vv.z; Ls[r][c + 3] = vv.w;
  __syncthreads();
  u16x4 o;
  o.x = f2bf(Ls[c + 0][r]);
  o.y = f2bf(Ls[c + 1][r]);
  o.z = f2bf(Ls[c + 2][r]);
  o.w = f2bf(Ls[c + 3][r]);
  *(u16x4*)(jb.dst + (size_t)(tn * 32 + r) * jb.K + tk * 32 + c) = o;
}

// ---------------- bf16 MFMA GEMM (64M x 128N, dbuf 2-phase, swizzled LDS) ---
// C[M=768][N] = A[768][K](bf16) * Wt[N][K](bf16)^T  (+bias)(+add f32)(relu)
// 256 threads = 4 waves (2Mx2N); per wave 32x64 output (acc 2x4 f32x4).
// BK=64, double-buffered: stage(next) || compute(cur), ONE barrier per step.
// XOR-swizzle via pre-swizzled global source (linear LDS dest + swz read).
struct GemmOp {
  const unsigned short* A;
  const unsigned short* B;   // Wt, row n, col k, stride ldb
  const float* bias;         // [N] or null
  const float* add;          // [768][N] f32 or null
  float* Cf;                 // or null
  unsigned short* Cb;        // or null
  int lda, ldb, N, K, relu;
};
struct GemmBatch { GemmOp op[5]; };

__global__ __launch_bounds__(256, 2) void gemm_mfma(GemmBatch batch) {
  const GemmOp g = batch.op[blockIdx.z];
  __shared__ unsigned short As[2][64 * 64];    // 2 x 8 KB
  __shared__ unsigned short Bs[2][128 * 64];   // 2 x 16 KB
  const int bm = blockIdx.y * 64, bn = blockIdx.x * 128;
  const int tid = threadIdx.x;
  const int l = tid & 63, w = tid >> 6;
  const int wr = (w >> 1) * 32, wc = (w & 1) * 64;
  const int lr = l & 15, lg = l >> 4;
  const int crow = l >> 3;
  const int scol = ((l & 7) ^ (l >> 3)) * 8;  // inv-swizzled source col (elems)
  const unsigned short* ap = g.A + (size_t)(bm + crow) * g.lda + scol;
  const unsigned short* bp = g.B + (size_t)(bn + crow) * g.ldb + scol;

  // prologue: stage tile 0 into buf 0
#pragma unroll
  for (int c = 0; c < 2; ++c) {
    const int ch = w * 2 + c;
    gload16(ap + (size_t)(ch * 8) * g.lda, &As[0][ch * 512 + l * 8]);
  }
#pragma unroll
  for (int c = 0; c < 4; ++c) {
    const int ch = w * 4 + c;
    gload16(bp + (size_t)(ch * 8) * g.ldb, &Bs[0][ch * 512 + l * 8]);
  }
  __syncthreads();

  f32x4 acc[2][4] = {};
  int cur = 0;
  for (int k0 = 0; k0 < g.K; k0 += 64) {
    // stage next tile into buf cur^1 (overlaps with compute below)
    if (k0 + 64 < g.K) {
      const int nb = cur ^ 1;
#pragma unroll
      for (int c = 0; c < 2; ++c) {
        const int ch = w * 2 + c;
        gload16(ap + (size_t)(ch * 8) * g.lda + k0 + 64,
                &As[nb][ch * 512 + l * 8]);
      }
#pragma unroll
      for (int c = 0; c < 4; ++c) {
        const int ch = w * 4 + c;
        gload16(bp + (size_t)(ch * 8) * g.ldb + k0 + 64,
                &Bs[nb][ch * 512 + l * 8]);
      }
    }
    const char* AsB = (const char*)As[cur];
    const char* BsB = (const char*)Bs[cur];
#pragma unroll
    for (int ks = 0; ks < 2; ++ks) {
      short8 af[2], bf[4];
#pragma unroll
      for (int i = 0; i < 2; ++i) {
        const int ra = wr + i * 16 + lr;
        af[i] = *(const short8*)(AsB +
                 ((ra * 128 + ks * 64 + lg * 16) ^ ((ra & 7) << 4)));
      }
#pragma unroll
      for (int j = 0; j < 4; ++j) {
        const int rb = wc + j * 16 + lr;
        bf[j] = *(const short8*)(BsB +
                 ((rb * 128 + ks * 64 + lg * 16) ^ ((rb & 7) << 4)));
      }
#pragma unroll
      for (int i = 0; i < 2; ++i)
#pragma unroll
        for (int j = 0; j < 4; ++j)
          acc[i][j] =
              __builtin_amdgcn_mfma_f32_16x16x32_bf16(af[i], bf[j], acc[i][j], 0, 0, 0);
    }
    __syncthreads();  // drains next-stage vmcnt + all reads of cur done
    cur ^= 1;
  }
  // epilogue: C/D layout col=lane&15, row=(lane>>4)*4+reg
#pragma unroll
  for (int j = 0; j < 4; ++j) {
    const int col = bn + wc + j * 16 + lr;
    const float bv = g.bias ? g.bias[col] : 0.0f;
#pragma unroll
    for (int i = 0; i < 2; ++i) {
#pragma unroll
      for (int ii = 0; ii < 4; ++ii) {
        const int row = bm + wr + i * 16 + lg * 4 + ii;
        float v = acc[i][j][ii] + bv;
        if (g.add) v += g.add[(size_t)row * g.N + col];
        if (g.relu) v = fmaxf(v, 0.0f);
        if (g.Cf) g.Cf[(size_t)row * g.N + col] = v;
        if (g.Cb) g.Cb[(size_t)row * g.N + col] = f2bf(v);
      }
    }
  }
}

// ---------------- decision gate, pass 1 v3 ----------------------------------
// Single-accumulator: PART[s][out] = sum_d relu(A1+A0) * (w2[d][1]-w2[d][0]).
// grid (32 d-splits x 64d, B=4, 9 pairs) = 1152 blocks; 4x4 outputs/thread.
__global__ __launch_bounds__(256) void decision_part(
    const float* __restrict__ A1, const float* __restrict__ A0,
    const float* __restrict__ w2, float* __restrict__ PART) {
  __shared__ float sA1[64][68];   // 64 rows x 64 d
  __shared__ float sA0[64][68];
  const int ds = blockIdx.x;      // d range [ds*64, ds*64+64)
  const int b = blockIdx.y, pp = blockIdx.z;
  const int i = pp / 3, j = pp % 3;
  const int tid = threadIdx.x;
  const int tq = tid >> 4, tk = tid & 15;
  const float* a1base = A1 + ((size_t)(j * 4 + b) * 64) * 2048 + ds * 64;
  const float* a0base = A0 + ((size_t)(i * 4 + b) * 64) * 2048 + ds * 64;
#pragma unroll
  for (int t = 0; t < 4; ++t) {
    const int row = t * 16 + tq;
    const int col = tk * 4;
    *(float4*)&sA1[row][col] = *(const float4*)(a1base + (size_t)row * 2048 + col);
    *(float4*)&sA0[row][col] = *(const float4*)(a0base + (size_t)row * 2048 + col);
  }
  __syncthreads();
  float acc[4][4] = {};
  const float* wbase = w2 + (size_t)ds * 128;  // [64 d][2] for this block
#pragma unroll 4
  for (int s4 = 0; s4 < 16; ++s4) {   // 4 d per iteration
    float4 wv0 = *(const float4*)(wbase + s4 * 8);
    float4 wv1 = *(const float4*)(wbase + s4 * 8 + 4);
    float wd0 = wv0.y - wv0.x, wd1 = wv0.w - wv0.z;
    float wd2 = wv1.y - wv1.x, wd3 = wv1.w - wv1.z;
    float4 a1v[4], a0v[4];
#pragma unroll
    for (int r = 0; r < 4; ++r) {
      a1v[r] = *(const float4*)&sA1[tq + 16 * r][s4 * 4];
      a0v[r] = *(const float4*)&sA0[tk + 16 * r][s4 * 4];
    }
#pragma unroll
    for (int qr = 0; qr < 4; ++qr)
#pragma unroll
      for (int kr = 0; kr < 4; ++kr) {
        float a = acc[qr][kr];
        a = fmaf(fmaxf(a1v[qr].x + a0v[kr].x, 0.f), wd0, a);
        a = fmaf(fmaxf(a1v[qr].y + a0v[kr].y, 0.f), wd1, a);
        a = fmaf(fmaxf(a1v[qr].z + a0v[kr].z, 0.f), wd2, a);
        a = fmaf(fmaxf(a1v[qr].w + a0v[kr].w, 0.f), wd3, a);
        acc[qr][kr] = a;
      }
  }
  float* outp = PART + (size_t)ds * 147456 + ((size_t)pp * 4 + b) * 4096;
#pragma unroll
  for (int qr = 0; qr < 4; ++qr)
#pragma unroll
    for (int kr = 0; kr < 4; ++kr)
      outp[(tq + 16 * qr) * 64 + (tk + 16 * kr)] = acc[qr][kr];
}

// ---------------- decision gate, pass 2: reduce + compare -------------------
__global__ __launch_bounds__(256) void decision_reduce(
    const float* __restrict__ PART, const float* __restrict__ b2,
    float* __restrict__ DEC) {
  const int out = blockIdx.x * 256 + threadIdx.x;
  float acc = 0.f;
#pragma unroll
  for (int s = 0; s < 32; ++s) acc += PART[(size_t)s * 147456 + out];
  const float thr = b2[0] - b2[1];
  DEC[out] = (acc > thr) ? NEGV : 0.f;
}

// ---------------- MFMA attention (full barrier discipline) ------------------
__global__ __launch_bounds__(256) void attn_mfma(
    const unsigned short* __restrict__ Qa, const unsigned short* __restrict__ Ka,
    const unsigned short* __restrict__ Va, const float* __restrict__ DEC,
    const int* __restrict__ mask, unsigned short* __restrict__ O) {
  __shared__ __align__(16) char sm[49408];
  char* KsP = sm;
  char* Vt = sm + 24576;
  float* invs = (float*)(sm + 49152);

  const int h = blockIdx.x, b = blockIdx.y, i = blockIdx.z;
  const int tid = threadIdx.x;
  const int l = tid & 63, w = tid >> 6;
  const int l15 = l & 15, lg = l >> 4;

#pragma unroll
  for (int rep = 0; rep < 6; ++rep) {
    int flat = rep * 256 + tid;
    int key = flat >> 3, c8 = flat & 7;
    int j = key >> 6, kl = key & 63;
    const size_t rowoff = (((size_t)(j * 4 + b) * 64 + kl) * 1024) + h * 64 + c8 * 8;
    u16x8 kv = *(const u16x8*)(Ka + rowoff);
    *(u16x8*)(KsP + ((key * 128 + c8 * 16) ^ ((key & 7) << 4))) = kv;
    u16x8 vv = *(const u16x8*)(Va + rowoff);
#pragma unroll
    for (int jj = 0; jj < 8; ++jj) {
      int d = c8 * 8 + jj;
      *(unsigned short*)(Vt + ((d * 384 + key * 2) ^ ((d & 7) << 4))) = vv[jj];
    }
  }

  const int qg = w * 16 + l15;
  const unsigned short* qsrc =
      Qa + (((size_t)(i * 4 + b) * 64 + qg) * 1024) + h * 64 + lg * 8;
  short8 qf0 = *(const short8*)(qsrc);
  short8 qf1 = *(const short8*)(qsrc + 32);

  __syncthreads();  // (1)

  f32x4 s[12];
#pragma unroll
  for (int t = 0; t < 12; ++t) {
    const int key = t * 16 + l15;
    const int swz = (key & 7) << 4;
    short8 kf0 = *(const short8*)(KsP + ((key * 128 + 0 + lg * 16) ^ swz));
    short8 kf1 = *(const short8*)(KsP + ((key * 128 + 64 + lg * 16) ^ swz));
    f32x4 z = {0.f, 0.f, 0.f, 0.f};
    z = __builtin_amdgcn_mfma_f32_16x16x32_bf16(kf0, qf0, z, 0, 0, 0);
    z = __builtin_amdgcn_mfma_f32_16x16x32_bf16(kf1, qf1, z, 0, 0, 0);
    s[t] = z;
  }

  int mk[4][4];
#pragma unroll
  for (int t4 = 0; t4 < 4; ++t4)
#pragma unroll
    for (int r = 0; r < 4; ++r)
      mk[t4][r] = mask[((size_t)b * 64 + qg) * 64 + t4 * 16 + lg * 4 + r];

  float mx = -3.0e38f;
#pragma unroll
  for (int t = 0; t < 12; ++t) {
    const float* dbase =
        DEC + (((size_t)(i * 3 + (t >> 2)) * 4 + b) * 4096) + qg * 64;
#pragma unroll
    for (int r = 0; r < 4; ++r) {
      const int kl = (t & 3) * 16 + lg * 4 + r;
      float sv = s[t][r] * 0.125f + dbase[kl];
      if (mk[t & 3][r] == 0) sv = NEGV;
      s[t][r] = sv;
      mx = fmaxf(mx, sv);
    }
  }
  mx = fmaxf(mx, __shfl_xor(mx, 16));
  mx = fmaxf(mx, __shfl_xor(mx, 32));
  float sum = 0.f;
#pragma unroll
  for (int t = 0; t < 12; ++t)
#pragma unroll
    for (int r = 0; r < 4; ++r) {
      float p = __expf(s[t][r] - mx);
      s[t][r] = p;
      sum += p;
    }
  sum += __shfl_xor(sum, 16);
  sum += __shfl_xor(sum, 32);
  if (l < 16) invs[w * 16 + l] = 1.0f / sum;

  __syncthreads();  // (2)

  char* Pmy = KsP + w * 6144;
  const int pswz = (l15 & 7) << 4;

#pragma unroll
  for (int t = 0; t < 12; ++t)
#pragma unroll
    for (int r = 0; r < 4; ++r) {
      const int key = t * 16 + lg * 4 + r;
      *(unsigned short*)(Pmy + ((l15 * 384 + key * 2) ^ pswz)) = f2bf(s[t][r]);
    }
  __syncthreads();  // (3)

  f32x4 o[4] = {};
#pragma unroll
  for (int kc = 0; kc < 6; ++kc) {
    short8 pf = *(const short8*)(Pmy + ((l15 * 384 + kc * 64 + lg * 16) ^ pswz));
#pragma unroll
    for (int dt = 0; dt < 4; ++dt) {
      const int d = dt * 16 + l15;
      short8 vf = *(const short8*)(Vt + ((d * 384 + kc * 64 + lg * 16) ^ ((d & 7) << 4)));
      o[dt] = __builtin_amdgcn_mfma_f32_16x16x32_bf16(pf, vf, o[dt], 0, 0, 0);
    }
  }
  __syncthreads();  // (4)

#pragma unroll
  for (int t = 0; t < 12; ++t)
#pragma unroll
    for (int r = 0; r < 4; ++r) {
      const int key = t * 16 + lg * 4 + r;
      float p = s[t][r];
      float lo = p - bf2f(f2bf(p));
      *(unsigned short*)(Pmy + ((l15 * 384 + key * 2) ^ pswz)) = f2bf(lo);
    }
  __syncthreads();  // (5)

#pragma unroll
  for (int kc = 0; kc < 6; ++kc) {
    short8 pf = *(const short8*)(Pmy + ((l15 * 384 + kc * 64 + lg * 16) ^ pswz));
#pragma unroll
    for (int dt = 0; dt < 4; ++dt) {
      const int d = dt * 16 + l15;
      short8 vf = *(const short8*)(Vt + ((d * 384 + kc * 64 + lg * 16) ^ ((d & 7) << 4)));
      o[dt] = __builtin_amdgcn_mfma_f32_16x16x32_bf16(pf, vf, o[dt], 0, 0, 0);
    }
  }

#pragma unroll
  for (int dt = 0; dt < 4; ++dt)
#pragma unroll
    for (int r = 0; r < 4; ++r) {
      const int ql = lg * 4 + r;
      const float inv = invs[w * 16 + ql];
      const int d = dt * 16 + l15;
      O[(((size_t)(i * 4 + b) * 64 + w * 16 + ql) * 1024) + h * 64 + d] =
          f2bf(o[dt][r] * inv);
    }
}

// ---------------- layer norm over rows of 1024 ------------------------------
__global__ __launch_bounds__(256) void ln_kernel(const float* __restrict__ X,
                                                 const float* __restrict__ g,
                                                 const float* __restrict__ be,
                                                 float* __restrict__ Y,
                                                 unsigned short* __restrict__ Yb) {
  __shared__ float rs[8];
  int row = blockIdx.x, tid = threadIdx.x;
  const float* x = X + (size_t)row * 1024 + tid * 4;
  float4 v = *(const float4*)x;
  float s = v.x + v.y + v.z + v.w;
  float s2 = v.x * v.x + v.y * v.y + v.z * v.z + v.w * v.w;
#pragma unroll
  for (int off = 32; off > 0; off >>= 1) {
    s += __shfl_down(s, off);
    s2 += __shfl_down(s2, off);
  }
  int lane = tid & 63, wid = tid >> 6;
  if (lane == 0) { rs[wid * 2] = s; rs[wid * 2 + 1] = s2; }
  __syncthreads();
  if (tid == 0) {
    float aa = rs[0] + rs[2] + rs[4] + rs[6];
    float cc = rs[1] + rs[3] + rs[5] + rs[7];
    rs[0] = aa; rs[1] = cc;
  }
  __syncthreads();
  float mu = rs[0] * (1.0f / 1024.0f);
  float var = rs[1] * (1.0f / 1024.0f) - mu * mu;
  var = fmaxf(var, 0.f);
  float inv = 1.0f / sqrtf(var + 1e-6f);
  float4 gv = *(const float4*)(g + tid * 4);
  float4 bv = *(const float4*)(be + tid * 4);
  float4 o;
  o.x = (v.x - mu) * inv * gv.x + bv.x;
  o.y = (v.y - mu) * inv * gv.y + bv.y;
  o.z = (v.z - mu) * inv * gv.z + bv.z;
  o.w = (v.w - mu) * inv * gv.w + bv.w;
  *(float4*)(Y + (size_t)row * 1024 + tid * 4) = o;
  if (Yb) {
    u16x4 ob;
    ob.x = f2bf(o.x); ob.y = f2bf(o.y); ob.z = f2bf(o.z); ob.w = f2bf(o.w);
    *(u16x4*)(Yb + (size_t)row * 1024 + tid * 4) = ob;
  }
}

// ---------------- fused FFN2 k-split reduce + LN2 ---------------------------
__global__ __launch_bounds__(256) void fsum_ln(
    const float* __restrict__ P, const float* __restrict__ bias,
    const float* __restrict__ add, const float* __restrict__ g,
    const float* __restrict__ be, float* __restrict__ Y) {
  __shared__ float rs[8];
  int row = blockIdx.x, tid = threadIdx.x;
  const int c = tid * 4;
  const size_t o = (size_t)row * 1024 + c;
  float4 p0 = *(const float4*)(P + o);
  float4 p1 = *(const float4*)(P + 786432 + o);
  float4 p2 = *(const float4*)(P + 2 * 786432 + o);
  float4 p3 = *(const float4*)(P + 3 * 786432 + o);
  float4 bs = *(const float4*)(bias + c);
  float4 ad = *(const float4*)(add + o);
  float4 v;
  v.x = ((p0.x + p1.x) + (p2.x + p3.x)) + bs.x + ad.x;
  v.y = ((p0.y + p1.y) + (p2.y + p3.y)) + bs.y + ad.y;
  v.z = ((p0.z + p1.z) + (p2.z + p3.z)) + bs.z + ad.z;
  v.w = ((p0.w + p1.w) + (p2.w + p3.w)) + bs.w + ad.w;
  float s = v.x + v.y + v.z + v.w;
  float s2 = v.x * v.x + v.y * v.y + v.z * v.z + v.w * v.w;
#pragma unroll
  for (int off = 32; off > 0; off >>= 1) {
    s += __shfl_down(s, off);
    s2 += __shfl_down(s2, off);
  }
  int lane = tid & 63, wid = tid >> 6;
  if (lane == 0) { rs[wid * 2] = s; rs[wid * 2 + 1] = s2; }
  __syncthreads();
  if (tid == 0) {
    float aa = rs[0] + rs[2] + rs[4] + rs[6];
    float cc = rs[1] + rs[3] + rs[5] + rs[7];
    rs[0] = aa; rs[1] = cc;
  }
  __syncthreads();
  float mu = rs[0] * (1.0f / 1024.0f);
  float var = rs[1] * (1.0f / 1024.0f) - mu * mu;
  var = fmaxf(var, 0.f);
  float inv = 1.0f / sqrtf(var + 1e-6f);
  float4 gv = *(const float4*)(g + c);
  float4 bv = *(const float4*)(be + c);
  float4 r;
  r.x = (v.x - mu) * inv * gv.x + bv.x;
  r.y = (v.y - mu) * inv * gv.y + bv.y;
  r.z = (v.z - mu) * inv * gv.z + bv.z;
  r.w = (v.w - mu) * inv * gv.w + bv.w;
  *(float4*)(Y + o) = r;
}

// ---------------------------------------------------------------------------
extern "C" void kernel_launch(void* const* d_in, const int* in_sizes, int n_in,
                              void* d_out, int out_size, void* d_ws,
                              size_t ws_size, hipStream_t stream) {
  const float* in_t = (const float*)d_in[0];
  const float* in_a = (const float*)d_in[1];
  const float* in_v = (const float*)d_in[2];
  const int* mask = (const int*)d_in[3];
  const float* w_qs = (const float*)d_in[4];
  const float* w_ks = (const float*)d_in[5];
  const float* w_vs = (const float*)d_in[6];
  const float* w_ds0 = (const float*)d_in[7];
  const float* w_ds1 = (const float*)d_in[8];
  const float* dc_w1 = (const float*)d_in[9];
  const float* dc_b1 = (const float*)d_in[10];
  const float* dc_w2 = (const float*)d_in[11];
  const float* dc_b2 = (const float*)d_in[12];
  const float* w_fc = (const float*)d_in[13];
  const float* ln1_g = (const float*)d_in[14];
  const float* ln1_b = (const float*)d_in[15];
  const float* ffn_w1 = (const float*)d_in[16];
  const float* ffn_b1 = (const float*)d_in[17];
  const float* ffn_w2 = (const float*)d_in[18];
  const float* ffn_b2 = (const float*)d_in[19];
  const float* ln2_g = (const float*)d_in[20];
  const float* ln2_b = (const float*)d_in[21];
  float* out = (float*)d_out;

  char* p = (char*)d_ws;
  auto alloc = [&](size_t bytes) {
    char* r = p;
    p += (bytes + 255) & ~(size_t)255;
    return r;
  };
  unsigned short* WQS = (unsigned short*)alloc(1024 * 1024 * 2);
  unsigned short* WKS = (unsigned short*)alloc(1024 * 1024 * 2);
  unsigned short* WVS = (unsigned short*)alloc(1024 * 1024 * 2);
  unsigned short* WD0 = (unsigned short*)alloc(1024 * 1024 * 2);
  unsigned short* WD1 = (unsigned short*)alloc(1024 * 1024 * 2);
  unsigned short* WW1 = (unsigned short*)alloc((size_t)2048 * 2048 * 2);
  unsigned short* WFC = (unsigned short*)alloc(1024 * 1024 * 2);
  unsigned short* WF1 = (unsigned short*)alloc((size_t)4096 * 1024 * 2);
  unsigned short* WF2 = (unsigned short*)alloc((size_t)1024 * 4096 * 2);
  float* Xf = (float*)alloc((size_t)786432 * 4);
  unsigned short* Xb = (unsigned short*)alloc((size_t)786432 * 2);
  unsigned short* Qb = (unsigned short*)alloc((size_t)786432 * 2);
  unsigned short* Kb = (unsigned short*)alloc((size_t)786432 * 2);
  unsigned short* Vb = (unsigned short*)alloc((size_t)786432 * 2);
  unsigned short* D0b = (unsigned short*)alloc((size_t)786432 * 2);
  unsigned short* D1b = (unsigned short*)alloc((size_t)786432 * 2);
  float* DEC = (float*)alloc((size_t)147456 * 4);
  unsigned short* OATTb = (unsigned short*)alloc((size_t)786432 * 2);
  float* PART = (float*)alloc((size_t)32 * 147456 * 4);  // 18.9 MB partials
  float* FPART = PART;  // reused after decision for FFN2 k-split
  char* U = alloc((size_t)14155776);
  float* A0f = (float*)U;
  float* A1f = (float*)(U + (size_t)6291456);
  float* F2 = (float*)U;
  float* O1f = (float*)(U + (size_t)3145728);
  unsigned short* O1b = (unsigned short*)(U + (size_t)6291456);
  unsigned short* Hfb = (unsigned short*)(U + (size_t)7864320);

  dim3 blk(256);

  WtJobs jobs;
  int ts = 0;
  auto setjob = [&](int idx, const float* s, unsigned short* d, int K, int N) {
    jobs.j[idx].src = s; jobs.j[idx].dst = d;
    jobs.j[idx].K = K; jobs.j[idx].N = N; jobs.j[idx].tstart = ts;
    ts += (K / 32) * (N / 32);
  };
  setjob(0, w_qs, WQS, 1024, 1024);
  setjob(1, w_ks, WKS, 1024, 1024);
  setjob(2, w_vs, WVS, 1024, 1024);
  setjob(3, w_ds0, WD0, 1024, 1024);
  setjob(4, w_ds1, WD1, 1024, 1024);
  setjob(5, dc_w1, WW1, 2048, 2048);
  setjob(6, w_fc, WFC, 1024, 1024);
  setjob(7, ffn_w1, WF1, 1024, 4096);
  setjob(8, ffn_w2, WF2, 4096, 1024);
  prep<<<dim3(768 + ts), blk, 0, stream>>>((const float4*)in_t,
                                           (const float4*)in_a,
                                           (const float4*)in_v,
                                           (float4*)Xf, (u16x4*)Xb, jobs);

  GemmBatch proj{};
  unsigned short* pouts[5] = {Qb, Kb, Vb, D0b, D1b};
  const unsigned short* pws[5] = {WQS, WKS, WVS, WD0, WD1};
  for (int z = 0; z < 5; ++z) {
    proj.op[z].A = Xb; proj.op[z].B = pws[z];
    proj.op[z].bias = nullptr; proj.op[z].add = nullptr;
    proj.op[z].Cf = nullptr; proj.op[z].Cb = pouts[z];
    proj.op[z].lda = 1024; proj.op[z].ldb = 1024;
    proj.op[z].N = 1024; proj.op[z].K = 1024; proj.op[z].relu = 0;
  }
  gemm_mfma<<<dim3(8, 12, 5), blk, 0, stream>>>(proj);

  GemmBatch pair{};
  pair.op[0].A = D0b; pair.op[0].B = WW1 + 1024;
  pair.op[0].bias = nullptr; pair.op[0].add = nullptr;
  pair.op[0].Cf = A0f; pair.op[0].Cb = nullptr;
  pair.op[0].lda = 1024; pair.op[0].ldb = 2048;
  pair.op[0].N = 2048; pair.op[0].K = 1024; pair.op[0].relu = 0;
  pair.op[1] = pair.op[0];
  pair.op[1].A = D1b; pair.op[1].B = WW1; pair.op[1].bias = dc_b1;
  pair.op[1].Cf = A1f;
  gemm_mfma<<<dim3(16, 12, 2), blk, 0, stream>>>(pair);

  decision_part<<<dim3(32, 4, 9), blk, 0, stream>>>(A1f, A0f, dc_w2, PART);
  decision_reduce<<<dim3(576), blk, 0, stream>>>(PART, dc_b2, DEC);

  attn_mfma<<<dim3(16, 4, 3), blk, 0, stream>>>(Qb, Kb, Vb, DEC, mask, OATTb);

  GemmBatch fc{};
  fc.op[0].A = OATTb; fc.op[0].B = WFC;
  fc.op[0].bias = nullptr; fc.op[0].add = Xf;
  fc.op[0].Cf = F2; fc.op[0].Cb = nullptr;
  fc.op[0].lda = 1024; fc.op[0].ldb = 1024;
  fc.op[0].N = 1024; fc.op[0].K = 1024; fc.op[0].relu = 0;
  gemm_mfma<<<dim3(8, 12, 1), blk, 0, stream>>>(fc);

  ln_kernel<<<dim3(768), blk, 0, stream>>>(F2, ln1_g, ln1_b, O1f, O1b);

  GemmBatch f1{};
  f1.op[0].A = O1b; f1.op[0].B = WF1;
  f1.op[0].bias = ffn_b1; f1.op[0].add = nullptr;
  f1.op[0].Cf = nullptr; f1.op[0].Cb = Hfb;
  f1.op[0].lda = 1024; f1.op[0].ldb = 1024;
  f1.op[0].N = 4096; f1.op[0].K = 1024; f1.op[0].relu = 1;
  gemm_mfma<<<dim3(32, 12, 1), blk, 0, stream>>>(f1);

  // FFN2 k-split x4: partials into FPART, then fused reduce+LN2
  GemmBatch f2{};
  for (int z = 0; z < 4; ++z) {
    f2.op[z].A = Hfb + (size_t)z * 1024;
    f2.op[z].B = WF2 + (size_t)z * 1024;
    f2.op[z].bias = nullptr; f2.op[z].add = nullptr;
    f2.op[z].Cf = FPART + (size_t)z * 786432; f2.op[z].Cb = nullptr;
    f2.op[z].lda = 4096; f2.op[z].ldb = 4096;
    f2.op[z].N = 1024; f2.op[z].K = 1024; f2.op[z].relu = 0;
  }
  gemm_mfma<<<dim3(8, 12, 4), blk, 0, stream>>>(f2);

  fsum_ln<<<dim3(768), blk, 0, stream>>>(FPART, ffn_b2, O1f, ln2_g, ln2_b, out);
}

// Round 12
// 151.316 us; speedup vs baseline: 1.0984x; 1.0984x over previous
//
#include <hip/hip_runtime.h>
#include <math.h>

// ---------------------------------------------------------------------------
// MMModel bf16-MFMA implementation. B=4, L=64, DM=1024, H=16, DK=DV=64,
// D=1024, DI=4096, nm=3. Row convention: row = (i*B + b)*L + l  (768 rows).
// ---------------------------------------------------------------------------

#define NEGV (-1000000000.0f)

typedef float f32x4 __attribute__((ext_vector_type(4)));
typedef short short8 __attribute__((ext_vector_type(8)));
typedef unsigned short u16x8 __attribute__((ext_vector_type(8)));
typedef unsigned short u16x4 __attribute__((ext_vector_type(4)));

typedef __attribute__((address_space(1))) const void glob_cv;
typedef __attribute__((address_space(3))) void lds_v;

static __device__ __forceinline__ unsigned short f2bf(float f) {
  unsigned u = __builtin_bit_cast(unsigned, f);
  u += 0x7fffu + ((u >> 16) & 1u);
  return (unsigned short)(u >> 16);
}
static __device__ __forceinline__ float bf2f(unsigned short h) {
  return __builtin_bit_cast(float, ((unsigned)h) << 16);
}

// async global->LDS, 16B per lane (linear dest = base + lane*16).
static __device__ __forceinline__ void gload16(const unsigned short* g,
                                               unsigned short* l) {
  __builtin_amdgcn_global_load_lds((glob_cv*)g, (lds_v*)l, 16, 0, 0);
}

// ---------------- prep: concat inputs + weight transpose/cast ---------------
// blocks [0,768): concat X (f32 + bf16). blocks [768, 768+ts): wt jobs.
struct WtJob { const float* src; unsigned short* dst; int K, N, tstart; };
struct WtJobs { WtJob j[9]; };

__global__ __launch_bounds__(256) void prep(const float4* __restrict__ t,
                                            const float4* __restrict__ a,
                                            const float4* __restrict__ v,
                                            float4* __restrict__ Xf,
                                            u16x4* __restrict__ Xb,
                                            WtJobs jobs) {
  __shared__ float Ls[32][33];
  const int tid = threadIdx.x;
  if (blockIdx.x < 768) {
    int id = blockIdx.x * 256 + tid;  // 768*256 float4s
    int m = id >> 16;
    int off = id & 65535;
    const float4* s = (m == 0) ? t : (m == 1) ? a : v;
    float4 val = s[off];
    Xf[id] = val;
    u16x4 bb;
    bb.x = f2bf(val.x); bb.y = f2bf(val.y);
    bb.z = f2bf(val.z); bb.w = f2bf(val.w);
    Xb[id] = bb;
    return;
  }
  const int bx = blockIdx.x - 768;
  int ji = 0;
#pragma unroll
  for (int tj = 1; tj < 9; ++tj)
    if (bx >= jobs.j[tj].tstart) ji = tj;
  const WtJob jb = jobs.j[ji];
  int local = bx - jb.tstart;
  int ntx = jb.N >> 5;
  int tk = local / ntx, tn = local - tk * ntx;
  const int r = tid >> 3, c = (tid & 7) * 4;
  float4 vv = *(const float4*)(jb.src + (size_t)(tk * 32 + r) * jb.N + tn * 32 + c);
  Ls[r][c + 0] = vv.x; Ls[r][c + 1] = vv.y;
  Ls[r][c + 2] = vv.z; Ls[r][c + 3] = vv.w;
  __syncthreads();
  u16x4 o;
  o.x = f2bf(Ls[c + 0][r]);
  o.y = f2bf(Ls[c + 1][r]);
  o.z = f2bf(Ls[c + 2][r]);
  o.w = f2bf(Ls[c + 3][r]);
  *(u16x4*)(jb.dst + (size_t)(tn * 32 + r) * jb.K + tk * 32 + c) = o;
}

// ---------------- bf16 MFMA GEMM (64M x 128N, BK=128, swizzled LDS) ---------
// C[M=768][N] = A[768][K](bf16) * Wt[N][K](bf16)^T  (+bias)(+add f32)(relu)
// 256 threads = 4 waves (2Mx2N); per wave 32x64 output (acc 2x4 f32x4).
// BK=128 halves barrier-drain count vs BK=64 (K=1024 -> 8 steps).
// LDS 48 KB single-buffered; XOR-swizzle via pre-swizzled global source
// (linear LDS dest + swz read). Per-element K-chain identical to BK=64.
struct GemmOp {
  const unsigned short* A;
  const unsigned short* B;   // Wt, row n, col k, stride ldb
  const float* bias;         // [N] or null
  const float* add;          // [768][N] f32 or null
  float* Cf;                 // or null
  unsigned short* Cb;        // or null
  int lda, ldb, N, K, relu;
};
struct GemmBatch { GemmOp op[5]; };

__global__ __launch_bounds__(256, 2) void gemm_mfma(GemmBatch batch) {
  const GemmOp g = batch.op[blockIdx.z];
  __shared__ unsigned short As[64 * 128];    // [m][k] 16 KB, 256B rows
  __shared__ unsigned short Bs[128 * 128];   // [n][k] 32 KB
  const int bm = blockIdx.y * 64, bn = blockIdx.x * 128;
  const int tid = threadIdx.x;
  const int l = tid & 63, w = tid >> 6;
  const int wr = (w >> 1) * 32, wc = (w & 1) * 64;
  const int lr = l & 15, lg = l >> 4;
  const int crow = l >> 4;            // row within 4-row wave-chunk (0..3)
  const int c16 = l & 15;             // 16B slot within 256B row
  // pre-swizzled source cols (elems) for even/odd chunk parity:
  // LDS[row][cb] holds global[row][cb ^ ((row&7)<<4)]; row&7 = (ch&1)*4+crow.
  const int scolE = 8 * (c16 ^ crow);
  const int scolO = 8 * (c16 ^ (4 + crow));
  const char* AsB = (const char*)As;
  const char* BsB = (const char*)Bs;
  f32x4 acc[2][4] = {};
  for (int k0 = 0; k0 < g.K; k0 += 128) {
    __syncthreads();  // previous compute reads done
    // A: 16 wave-chunks of 4 rows; wave w stages chunks w*4..w*4+3
#pragma unroll
    for (int c = 0; c < 4; ++c) {
      const int ch = w * 4 + c;
      const int sc = (ch & 1) ? scolO : scolE;
      gload16(g.A + (size_t)(bm + ch * 4 + crow) * g.lda + k0 + sc,
              &As[ch * 512 + l * 8]);
    }
    // B: 32 wave-chunks of 4 rows; wave w stages chunks w*8..w*8+7
#pragma unroll
    for (int c = 0; c < 8; ++c) {
      const int ch = w * 8 + c;
      const int sc = (ch & 1) ? scolO : scolE;
      gload16(g.B + (size_t)(bn + ch * 4 + crow) * g.ldb + k0 + sc,
              &Bs[ch * 512 + l * 8]);
    }
    __syncthreads();  // compiler drains vmcnt(0) before barrier
#pragma unroll
    for (int ks = 0; ks < 4; ++ks) {
      short8 af[2], bf[4];
#pragma unroll
      for (int i = 0; i < 2; ++i) {
        const int ra = wr + i * 16 + lr;
        af[i] = *(const short8*)(AsB +
                 ((ra * 256 + ks * 64 + lg * 16) ^ ((ra & 7) << 4)));
      }
#pragma unroll
      for (int j = 0; j < 4; ++j) {
        const int rb = wc + j * 16 + lr;
        bf[j] = *(const short8*)(BsB +
                 ((rb * 256 + ks * 64 + lg * 16) ^ ((rb & 7) << 4)));
      }
#pragma unroll
      for (int i = 0; i < 2; ++i)
#pragma unroll
        for (int j = 0; j < 4; ++j)
          acc[i][j] =
              __builtin_amdgcn_mfma_f32_16x16x32_bf16(af[i], bf[j], acc[i][j], 0, 0, 0);
    }
  }
  // epilogue: C/D layout col=lane&15, row=(lane>>4)*4+reg
#pragma unroll
  for (int j = 0; j < 4; ++j) {
    const int col = bn + wc + j * 16 + lr;
    const float bv = g.bias ? g.bias[col] : 0.0f;
#pragma unroll
    for (int i = 0; i < 2; ++i) {
#pragma unroll
      for (int ii = 0; ii < 4; ++ii) {
        const int row = bm + wr + i * 16 + lg * 4 + ii;
        float v = acc[i][j][ii] + bv;
        if (g.add) v += g.add[(size_t)row * g.N + col];
        if (g.relu) v = fmaxf(v, 0.0f);
        if (g.Cf) g.Cf[(size_t)row * g.N + col] = v;
        if (g.Cb) g.Cb[(size_t)row * g.N + col] = f2bf(v);
      }
    }
  }
}

// ---------------- decision gate, pass 1 v3 ----------------------------------
// Single-accumulator: PART[s][out] = sum_d relu(A1+A0) * (w2[d][1]-w2[d][0]).
// grid (32 d-splits x 64d, B=4, 9 pairs) = 1152 blocks; 4x4 outputs/thread.
__global__ __launch_bounds__(256) void decision_part(
    const float* __restrict__ A1, const float* __restrict__ A0,
    const float* __restrict__ w2, float* __restrict__ PART) {
  __shared__ float sA1[64][68];   // 64 rows x 64 d
  __shared__ float sA0[64][68];
  const int ds = blockIdx.x;      // d range [ds*64, ds*64+64)
  const int b = blockIdx.y, pp = blockIdx.z;
  const int i = pp / 3, j = pp % 3;
  const int tid = threadIdx.x;
  const int tq = tid >> 4, tk = tid & 15;
  const float* a1base = A1 + ((size_t)(j * 4 + b) * 64) * 2048 + ds * 64;
  const float* a0base = A0 + ((size_t)(i * 4 + b) * 64) * 2048 + ds * 64;
#pragma unroll
  for (int t = 0; t < 4; ++t) {
    const int row = t * 16 + tq;
    const int col = tk * 4;
    *(float4*)&sA1[row][col] = *(const float4*)(a1base + (size_t)row * 2048 + col);
    *(float4*)&sA0[row][col] = *(const float4*)(a0base + (size_t)row * 2048 + col);
  }
  __syncthreads();
  float acc[4][4] = {};
  const float* wbase = w2 + (size_t)ds * 128;  // [64 d][2] for this block
#pragma unroll 4
  for (int s4 = 0; s4 < 16; ++s4) {   // 4 d per iteration
    float4 wv0 = *(const float4*)(wbase + s4 * 8);
    float4 wv1 = *(const float4*)(wbase + s4 * 8 + 4);
    float wd0 = wv0.y - wv0.x, wd1 = wv0.w - wv0.z;
    float wd2 = wv1.y - wv1.x, wd3 = wv1.w - wv1.z;
    float4 a1v[4], a0v[4];
#pragma unroll
    for (int r = 0; r < 4; ++r) {
      a1v[r] = *(const float4*)&sA1[tq + 16 * r][s4 * 4];
      a0v[r] = *(const float4*)&sA0[tk + 16 * r][s4 * 4];
    }
#pragma unroll
    for (int qr = 0; qr < 4; ++qr)
#pragma unroll
      for (int kr = 0; kr < 4; ++kr) {
        float a = acc[qr][kr];
        a = fmaf(fmaxf(a1v[qr].x + a0v[kr].x, 0.f), wd0, a);
        a = fmaf(fmaxf(a1v[qr].y + a0v[kr].y, 0.f), wd1, a);
        a = fmaf(fmaxf(a1v[qr].z + a0v[kr].z, 0.f), wd2, a);
        a = fmaf(fmaxf(a1v[qr].w + a0v[kr].w, 0.f), wd3, a);
        acc[qr][kr] = a;
      }
  }
  float* outp = PART + (size_t)ds * 147456 + ((size_t)pp * 4 + b) * 4096;
#pragma unroll
  for (int qr = 0; qr < 4; ++qr)
#pragma unroll
    for (int kr = 0; kr < 4; ++kr)
      outp[(tq + 16 * qr) * 64 + (tk + 16 * kr)] = acc[qr][kr];
}

// ---------------- decision gate, pass 2: reduce + compare -------------------
__global__ __launch_bounds__(256) void decision_reduce(
    const float* __restrict__ PART, const float* __restrict__ b2,
    float* __restrict__ DEC) {
  const int out = blockIdx.x * 256 + threadIdx.x;
  float acc = 0.f;
#pragma unroll
  for (int s = 0; s < 32; ++s) acc += PART[(size_t)s * 147456 + out];
  const float thr = b2[0] - b2[1];
  DEC[out] = (acc > thr) ? NEGV : 0.f;
}

// ---------------- MFMA attention (full barrier discipline) ------------------
__global__ __launch_bounds__(256) void attn_mfma(
    const unsigned short* __restrict__ Qa, const unsigned short* __restrict__ Ka,
    const unsigned short* __restrict__ Va, const float* __restrict__ DEC,
    const int* __restrict__ mask, unsigned short* __restrict__ O) {
  __shared__ __align__(16) char sm[49408];
  char* KsP = sm;
  char* Vt = sm + 24576;
  float* invs = (float*)(sm + 49152);

  const int h = blockIdx.x, b = blockIdx.y, i = blockIdx.z;
  const int tid = threadIdx.x;
  const int l = tid & 63, w = tid >> 6;
  const int l15 = l & 15, lg = l >> 4;

#pragma unroll
  for (int rep = 0; rep < 6; ++rep) {
    int flat = rep * 256 + tid;
    int key = flat >> 3, c8 = flat & 7;
    int j = key >> 6, kl = key & 63;
    const size_t rowoff = (((size_t)(j * 4 + b) * 64 + kl) * 1024) + h * 64 + c8 * 8;
    u16x8 kv = *(const u16x8*)(Ka + rowoff);
    *(u16x8*)(KsP + ((key * 128 + c8 * 16) ^ ((key & 7) << 4))) = kv;
    u16x8 vv = *(const u16x8*)(Va + rowoff);
#pragma unroll
    for (int jj = 0; jj < 8; ++jj) {
      int d = c8 * 8 + jj;
      *(unsigned short*)(Vt + ((d * 384 + key * 2) ^ ((d & 7) << 4))) = vv[jj];
    }
  }

  const int qg = w * 16 + l15;
  const unsigned short* qsrc =
      Qa + (((size_t)(i * 4 + b) * 64 + qg) * 1024) + h * 64 + lg * 8;
  short8 qf0 = *(const short8*)(qsrc);
  short8 qf1 = *(const short8*)(qsrc + 32);

  __syncthreads();  // (1)

  f32x4 s[12];
#pragma unroll
  for (int t = 0; t < 12; ++t) {
    const int key = t * 16 + l15;
    const int swz = (key & 7) << 4;
    short8 kf0 = *(const short8*)(KsP + ((key * 128 + 0 + lg * 16) ^ swz));
    short8 kf1 = *(const short8*)(KsP + ((key * 128 + 64 + lg * 16) ^ swz));
    f32x4 z = {0.f, 0.f, 0.f, 0.f};
    z = __builtin_amdgcn_mfma_f32_16x16x32_bf16(kf0, qf0, z, 0, 0, 0);
    z = __builtin_amdgcn_mfma_f32_16x16x32_bf16(kf1, qf1, z, 0, 0, 0);
    s[t] = z;
  }

  int mk[4][4];
#pragma unroll
  for (int t4 = 0; t4 < 4; ++t4)
#pragma unroll
    for (int r = 0; r < 4; ++r)
      mk[t4][r] = mask[((size_t)b * 64 + qg) * 64 + t4 * 16 + lg * 4 + r];

  float mx = -3.0e38f;
#pragma unroll
  for (int t = 0; t < 12; ++t) {
    const float* dbase =
        DEC + (((size_t)(i * 3 + (t >> 2)) * 4 + b) * 4096) + qg * 64;
#pragma unroll
    for (int r = 0; r < 4; ++r) {
      const int kl = (t & 3) * 16 + lg * 4 + r;
      float sv = s[t][r] * 0.125f + dbase[kl];
      if (mk[t & 3][r] == 0) sv = NEGV;
      s[t][r] = sv;
      mx = fmaxf(mx, sv);
    }
  }
  mx = fmaxf(mx, __shfl_xor(mx, 16));
  mx = fmaxf(mx, __shfl_xor(mx, 32));
  float sum = 0.f;
#pragma unroll
  for (int t = 0; t < 12; ++t)
#pragma unroll
    for (int r = 0; r < 4; ++r) {
      float p = __expf(s[t][r] - mx);
      s[t][r] = p;
      sum += p;
    }
  sum += __shfl_xor(sum, 16);
  sum += __shfl_xor(sum, 32);
  if (l < 16) invs[w * 16 + l] = 1.0f / sum;

  __syncthreads();  // (2)

  char* Pmy = KsP + w * 6144;
  const int pswz = (l15 & 7) << 4;

#pragma unroll
  for (int t = 0; t < 12; ++t)
#pragma unroll
    for (int r = 0; r < 4; ++r) {
      const int key = t * 16 + lg * 4 + r;
      *(unsigned short*)(Pmy + ((l15 * 384 + key * 2) ^ pswz)) = f2bf(s[t][r]);
    }
  __syncthreads();  // (3)

  f32x4 o[4] = {};
#pragma unroll
  for (int kc = 0; kc < 6; ++kc) {
    short8 pf = *(const short8*)(Pmy + ((l15 * 384 + kc * 64 + lg * 16) ^ pswz));
#pragma unroll
    for (int dt = 0; dt < 4; ++dt) {
      const int d = dt * 16 + l15;
      short8 vf = *(const short8*)(Vt + ((d * 384 + kc * 64 + lg * 16) ^ ((d & 7) << 4)));
      o[dt] = __builtin_amdgcn_mfma_f32_16x16x32_bf16(pf, vf, o[dt], 0, 0, 0);
    }
  }
  __syncthreads();  // (4)

#pragma unroll
  for (int t = 0; t < 12; ++t)
#pragma unroll
    for (int r = 0; r < 4; ++r) {
      const int key = t * 16 + lg * 4 + r;
      float p = s[t][r];
      float lo = p - bf2f(f2bf(p));
      *(unsigned short*)(Pmy + ((l15 * 384 + key * 2) ^ pswz)) = f2bf(lo);
    }
  __syncthreads();  // (5)

#pragma unroll
  for (int kc = 0; kc < 6; ++kc) {
    short8 pf = *(const short8*)(Pmy + ((l15 * 384 + kc * 64 + lg * 16) ^ pswz));
#pragma unroll
    for (int dt = 0; dt < 4; ++dt) {
      const int d = dt * 16 + l15;
      short8 vf = *(const short8*)(Vt + ((d * 384 + kc * 64 + lg * 16) ^ ((d & 7) << 4)));
      o[dt] = __builtin_amdgcn_mfma_f32_16x16x32_bf16(pf, vf, o[dt], 0, 0, 0);
    }
  }

#pragma unroll
  for (int dt = 0; dt < 4; ++dt)
#pragma unroll
    for (int r = 0; r < 4; ++r) {
      const int ql = lg * 4 + r;
      const float inv = invs[w * 16 + ql];
      const int d = dt * 16 + l15;
      O[(((size_t)(i * 4 + b) * 64 + w * 16 + ql) * 1024) + h * 64 + d] =
          f2bf(o[dt][r] * inv);
    }
}

// ---------------- layer norm over rows of 1024 ------------------------------
__global__ __launch_bounds__(256) void ln_kernel(const float* __restrict__ X,
                                                 const float* __restrict__ g,
                                                 const float* __restrict__ be,
                                                 float* __restrict__ Y,
                                                 unsigned short* __restrict__ Yb) {
  __shared__ float rs[8];
  int row = blockIdx.x, tid = threadIdx.x;
  const float* x = X + (size_t)row * 1024 + tid * 4;
  float4 v = *(const float4*)x;
  float s = v.x + v.y + v.z + v.w;
  float s2 = v.x * v.x + v.y * v.y + v.z * v.z + v.w * v.w;
#pragma unroll
  for (int off = 32; off > 0; off >>= 1) {
    s += __shfl_down(s, off);
    s2 += __shfl_down(s2, off);
  }
  int lane = tid & 63, wid = tid >> 6;
  if (lane == 0) { rs[wid * 2] = s; rs[wid * 2 + 1] = s2; }
  __syncthreads();
  if (tid == 0) {
    float aa = rs[0] + rs[2] + rs[4] + rs[6];
    float cc = rs[1] + rs[3] + rs[5] + rs[7];
    rs[0] = aa; rs[1] = cc;
  }
  __syncthreads();
  float mu = rs[0] * (1.0f / 1024.0f);
  float var = rs[1] * (1.0f / 1024.0f) - mu * mu;
  var = fmaxf(var, 0.f);
  float inv = 1.0f / sqrtf(var + 1e-6f);
  float4 gv = *(const float4*)(g + tid * 4);
  float4 bv = *(const float4*)(be + tid * 4);
  float4 o;
  o.x = (v.x - mu) * inv * gv.x + bv.x;
  o.y = (v.y - mu) * inv * gv.y + bv.y;
  o.z = (v.z - mu) * inv * gv.z + bv.z;
  o.w = (v.w - mu) * inv * gv.w + bv.w;
  *(float4*)(Y + (size_t)row * 1024 + tid * 4) = o;
  if (Yb) {
    u16x4 ob;
    ob.x = f2bf(o.x); ob.y = f2bf(o.y); ob.z = f2bf(o.z); ob.w = f2bf(o.w);
    *(u16x4*)(Yb + (size_t)row * 1024 + tid * 4) = ob;
  }
}

// ---------------- fused FFN2 k-split reduce + LN2 ---------------------------
__global__ __launch_bounds__(256) void fsum_ln(
    const float* __restrict__ P, const float* __restrict__ bias,
    const float* __restrict__ add, const float* __restrict__ g,
    const float* __restrict__ be, float* __restrict__ Y) {
  __shared__ float rs[8];
  int row = blockIdx.x, tid = threadIdx.x;
  const int c = tid * 4;
  const size_t o = (size_t)row * 1024 + c;
  float4 p0 = *(const float4*)(P + o);
  float4 p1 = *(const float4*)(P + 786432 + o);
  float4 p2 = *(const float4*)(P + 2 * 786432 + o);
  float4 p3 = *(const float4*)(P + 3 * 786432 + o);
  float4 bs = *(const float4*)(bias + c);
  float4 ad = *(const float4*)(add + o);
  float4 v;
  v.x = ((p0.x + p1.x) + (p2.x + p3.x)) + bs.x + ad.x;
  v.y = ((p0.y + p1.y) + (p2.y + p3.y)) + bs.y + ad.y;
  v.z = ((p0.z + p1.z) + (p2.z + p3.z)) + bs.z + ad.z;
  v.w = ((p0.w + p1.w) + (p2.w + p3.w)) + bs.w + ad.w;
  float s = v.x + v.y + v.z + v.w;
  float s2 = v.x * v.x + v.y * v.y + v.z * v.z + v.w * v.w;
#pragma unroll
  for (int off = 32; off > 0; off >>= 1) {
    s += __shfl_down(s, off);
    s2 += __shfl_down(s2, off);
  }
  int lane = tid & 63, wid = tid >> 6;
  if (lane == 0) { rs[wid * 2] = s; rs[wid * 2 + 1] = s2; }
  __syncthreads();
  if (tid == 0) {
    float aa = rs[0] + rs[2] + rs[4] + rs[6];
    float cc = rs[1] + rs[3] + rs[5] + rs[7];
    rs[0] = aa; rs[1] = cc;
  }
  __syncthreads();
  float mu = rs[0] * (1.0f / 1024.0f);
  float var = rs[1] * (1.0f / 1024.0f) - mu * mu;
  var = fmaxf(var, 0.f);
  float inv = 1.0f / sqrtf(var + 1e-6f);
  float4 gv = *(const float4*)(g + c);
  float4 bv = *(const float4*)(be + c);
  float4 r;
  r.x = (v.x - mu) * inv * gv.x + bv.x;
  r.y = (v.y - mu) * inv * gv.y + bv.y;
  r.z = (v.z - mu) * inv * gv.z + bv.z;
  r.w = (v.w - mu) * inv * gv.w + bv.w;
  *(float4*)(Y + o) = r;
}

// ---------------------------------------------------------------------------
extern "C" void kernel_launch(void* const* d_in, const int* in_sizes, int n_in,
                              void* d_out, int out_size, void* d_ws,
                              size_t ws_size, hipStream_t stream) {
  const float* in_t = (const float*)d_in[0];
  const float* in_a = (const float*)d_in[1];
  const float* in_v = (const float*)d_in[2];
  const int* mask = (const int*)d_in[3];
  const float* w_qs = (const float*)d_in[4];
  const float* w_ks = (const float*)d_in[5];
  const float* w_vs = (const float*)d_in[6];
  const float* w_ds0 = (const float*)d_in[7];
  const float* w_ds1 = (const float*)d_in[8];
  const float* dc_w1 = (const float*)d_in[9];
  const float* dc_b1 = (const float*)d_in[10];
  const float* dc_w2 = (const float*)d_in[11];
  const float* dc_b2 = (const float*)d_in[12];
  const float* w_fc = (const float*)d_in[13];
  const float* ln1_g = (const float*)d_in[14];
  const float* ln1_b = (const float*)d_in[15];
  const float* ffn_w1 = (const float*)d_in[16];
  const float* ffn_b1 = (const float*)d_in[17];
  const float* ffn_w2 = (const float*)d_in[18];
  const float* ffn_b2 = (const float*)d_in[19];
  const float* ln2_g = (const float*)d_in[20];
  const float* ln2_b = (const float*)d_in[21];
  float* out = (float*)d_out;

  char* p = (char*)d_ws;
  auto alloc = [&](size_t bytes) {
    char* r = p;
    p += (bytes + 255) & ~(size_t)255;
    return r;
  };
  unsigned short* WQS = (unsigned short*)alloc(1024 * 1024 * 2);
  unsigned short* WKS = (unsigned short*)alloc(1024 * 1024 * 2);
  unsigned short* WVS = (unsigned short*)alloc(1024 * 1024 * 2);
  unsigned short* WD0 = (unsigned short*)alloc(1024 * 1024 * 2);
  unsigned short* WD1 = (unsigned short*)alloc(1024 * 1024 * 2);
  unsigned short* WW1 = (unsigned short*)alloc((size_t)2048 * 2048 * 2);
  unsigned short* WFC = (unsigned short*)alloc(1024 * 1024 * 2);
  unsigned short* WF1 = (unsigned short*)alloc((size_t)4096 * 1024 * 2);
  unsigned short* WF2 = (unsigned short*)alloc((size_t)1024 * 4096 * 2);
  float* Xf = (float*)alloc((size_t)786432 * 4);
  unsigned short* Xb = (unsigned short*)alloc((size_t)786432 * 2);
  unsigned short* Qb = (unsigned short*)alloc((size_t)786432 * 2);
  unsigned short* Kb = (unsigned short*)alloc((size_t)786432 * 2);
  unsigned short* Vb = (unsigned short*)alloc((size_t)786432 * 2);
  unsigned short* D0b = (unsigned short*)alloc((size_t)786432 * 2);
  unsigned short* D1b = (unsigned short*)alloc((size_t)786432 * 2);
  float* DEC = (float*)alloc((size_t)147456 * 4);
  unsigned short* OATTb = (unsigned short*)alloc((size_t)786432 * 2);
  float* PART = (float*)alloc((size_t)32 * 147456 * 4);  // 18.9 MB partials
  float* FPART = PART;  // reused after decision for FFN2 k-split
  char* U = alloc((size_t)14155776);
  float* A0f = (float*)U;
  float* A1f = (float*)(U + (size_t)6291456);
  float* F2 = (float*)U;
  float* O1f = (float*)(U + (size_t)3145728);
  unsigned short* O1b = (unsigned short*)(U + (size_t)6291456);
  unsigned short* Hfb = (unsigned short*)(U + (size_t)7864320);

  dim3 blk(256);

  WtJobs jobs;
  int ts = 0;
  auto setjob = [&](int idx, const float* s, unsigned short* d, int K, int N) {
    jobs.j[idx].src = s; jobs.j[idx].dst = d;
    jobs.j[idx].K = K; jobs.j[idx].N = N; jobs.j[idx].tstart = ts;
    ts += (K / 32) * (N / 32);
  };
  setjob(0, w_qs, WQS, 1024, 1024);
  setjob(1, w_ks, WKS, 1024, 1024);
  setjob(2, w_vs, WVS, 1024, 1024);
  setjob(3, w_ds0, WD0, 1024, 1024);
  setjob(4, w_ds1, WD1, 1024, 1024);
  setjob(5, dc_w1, WW1, 2048, 2048);
  setjob(6, w_fc, WFC, 1024, 1024);
  setjob(7, ffn_w1, WF1, 1024, 4096);
  setjob(8, ffn_w2, WF2, 4096, 1024);
  prep<<<dim3(768 + ts), blk, 0, stream>>>((const float4*)in_t,
                                           (const float4*)in_a,
                                           (const float4*)in_v,
                                           (float4*)Xf, (u16x4*)Xb, jobs);

  GemmBatch proj{};
  unsigned short* pouts[5] = {Qb, Kb, Vb, D0b, D1b};
  const unsigned short* pws[5] = {WQS, WKS, WVS, WD0, WD1};
  for (int z = 0; z < 5; ++z) {
    proj.op[z].A = Xb; proj.op[z].B = pws[z];
    proj.op[z].bias = nullptr; proj.op[z].add = nullptr;
    proj.op[z].Cf = nullptr; proj.op[z].Cb = pouts[z];
    proj.op[z].lda = 1024; proj.op[z].ldb = 1024;
    proj.op[z].N = 1024; proj.op[z].K = 1024; proj.op[z].relu = 0;
  }
  gemm_mfma<<<dim3(8, 12, 5), blk, 0, stream>>>(proj);

  GemmBatch pair{};
  pair.op[0].A = D0b; pair.op[0].B = WW1 + 1024;
  pair.op[0].bias = nullptr; pair.op[0].add = nullptr;
  pair.op[0].Cf = A0f; pair.op[0].Cb = nullptr;
  pair.op[0].lda = 1024; pair.op[0].ldb = 2048;
  pair.op[0].N = 2048; pair.op[0].K = 1024; pair.op[0].relu = 0;
  pair.op[1] = pair.op[0];
  pair.op[1].A = D1b; pair.op[1].B = WW1; pair.op[1].bias = dc_b1;
  pair.op[1].Cf = A1f;
  gemm_mfma<<<dim3(16, 12, 2), blk, 0, stream>>>(pair);

  decision_part<<<dim3(32, 4, 9), blk, 0, stream>>>(A1f, A0f, dc_w2, PART);
  decision_reduce<<<dim3(576), blk, 0, stream>>>(PART, dc_b2, DEC);

  attn_mfma<<<dim3(16, 4, 3), blk, 0, stream>>>(Qb, Kb, Vb, DEC, mask, OATTb);

  GemmBatch fc{};
  fc.op[0].A = OATTb; fc.op[0].B = WFC;
  fc.op[0].bias = nullptr; fc.op[0].add = Xf;
  fc.op[0].Cf = F2; fc.op[0].Cb = nullptr;
  fc.op[0].lda = 1024; fc.op[0].ldb = 1024;
  fc.op[0].N = 1024; fc.op[0].K = 1024; fc.op[0].relu = 0;
  gemm_mfma<<<dim3(8, 12, 1), blk, 0, stream>>>(fc);

  ln_kernel<<<dim3(768), blk, 0, stream>>>(F2, ln1_g, ln1_b, O1f, O1b);

  GemmBatch f1{};
  f1.op[0].A = O1b; f1.op[0].B = WF1;
  f1.op[0].bias = ffn_b1; f1.op[0].add = nullptr;
  f1.op[0].Cf = nullptr; f1.op[0].Cb = Hfb;
  f1.op[0].lda = 1024; f1.op[0].ldb = 1024;
  f1.op[0].N = 4096; f1.op[0].K = 1024; f1.op[0].relu = 1;
  gemm_mfma<<<dim3(32, 12, 1), blk, 0, stream>>>(f1);

  // FFN2 k-split x4: partials into FPART, then fused reduce+LN2
  GemmBatch f2{};
  for (int z = 0; z < 4; ++z) {
    f2.op[z].A = Hfb + (size_t)z * 1024;
    f2.op[z].B = WF2 + (size_t)z * 1024;
    f2.op[z].bias = nullptr; f2.op[z].add = nullptr;
    f2.op[z].Cf = FPART + (size_t)z * 786432; f2.op[z].Cb = nullptr;
    f2.op[z].lda = 4096; f2.op[z].ldb = 4096;
    f2.op[z].N = 1024; f2.op[z].K = 1024; f2.op[z].relu = 0;
  }
  gemm_mfma<<<dim3(8, 12, 4), blk, 0, stream>>>(f2);

  fsum_ln<<<dim3(768), blk, 0, stream>>>(FPART, ffn_b2, O1f, ln2_g, ln2_b, out);
}

// Round 13
// 143.019 us; speedup vs baseline: 1.1621x; 1.0580x over previous
//
#include <hip/hip_runtime.h>
#include <math.h>

// ---------------------------------------------------------------------------
// MMModel bf16-MFMA implementation. B=4, L=64, DM=1024, H=16, DK=DV=64,
// D=1024, DI=4096, nm=3. Row convention: row = (i*B + b)*L + l  (768 rows).
// ---------------------------------------------------------------------------

#define NEGV (-1000000000.0f)

typedef float f32x4 __attribute__((ext_vector_type(4)));
typedef short short8 __attribute__((ext_vector_type(8)));
typedef unsigned short u16x8 __attribute__((ext_vector_type(8)));
typedef unsigned short u16x4 __attribute__((ext_vector_type(4)));

typedef __attribute__((address_space(1))) const void glob_cv;
typedef __attribute__((address_space(3))) void lds_v;

static __device__ __forceinline__ unsigned short f2bf(float f) {
  unsigned u = __builtin_bit_cast(unsigned, f);
  u += 0x7fffu + ((u >> 16) & 1u);
  return (unsigned short)(u >> 16);
}
static __device__ __forceinline__ float bf2f(unsigned short h) {
  return __builtin_bit_cast(float, ((unsigned)h) << 16);
}

// async global->LDS, 16B per lane (linear dest = base + lane*16).
static __device__ __forceinline__ void gload16(const unsigned short* g,
                                               unsigned short* l) {
  __builtin_amdgcn_global_load_lds((glob_cv*)g, (lds_v*)l, 16, 0, 0);
}

// ---------------- prep: concat inputs + weight transpose/cast ---------------
// blocks [0,768): concat X (f32 + bf16). blocks [768, 768+ts): wt jobs.
struct WtJob { const float* src; unsigned short* dst; int K, N, tstart; };
struct WtJobs { WtJob j[9]; };

__global__ __launch_bounds__(256) void prep(const float4* __restrict__ t,
                                            const float4* __restrict__ a,
                                            const float4* __restrict__ v,
                                            float4* __restrict__ Xf,
                                            u16x4* __restrict__ Xb,
                                            WtJobs jobs) {
  __shared__ float Ls[32][33];
  const int tid = threadIdx.x;
  if (blockIdx.x < 768) {
    int id = blockIdx.x * 256 + tid;  // 768*256 float4s
    int m = id >> 16;
    int off = id & 65535;
    const float4* s = (m == 0) ? t : (m == 1) ? a : v;
    float4 val = s[off];
    Xf[id] = val;
    u16x4 bb;
    bb.x = f2bf(val.x); bb.y = f2bf(val.y);
    bb.z = f2bf(val.z); bb.w = f2bf(val.w);
    Xb[id] = bb;
    return;
  }
  const int bx = blockIdx.x - 768;
  int ji = 0;
#pragma unroll
  for (int tj = 1; tj < 9; ++tj)
    if (bx >= jobs.j[tj].tstart) ji = tj;
  const WtJob jb = jobs.j[ji];
  int local = bx - jb.tstart;
  int ntx = jb.N >> 5;
  int tk = local / ntx, tn = local - tk * ntx;
  const int r = tid >> 3, c = (tid & 7) * 4;
  float4 vv = *(const float4*)(jb.src + (size_t)(tk * 32 + r) * jb.N + tn * 32 + c);
  Ls[r][c + 0] = vv.x; Ls[r][c + 1] = vv.y;
  Ls[r][c + 2] = vv.z; Ls[r][c + 3] = vv.w;
  __syncthreads();
  u16x4 o;
  o.x = f2bf(Ls[c + 0][r]);
  o.y = f2bf(Ls[c + 1][r]);
  o.z = f2bf(Ls[c + 2][r]);
  o.w = f2bf(Ls[c + 3][r]);
  *(u16x4*)(jb.dst + (size_t)(tn * 32 + r) * jb.K + tk * 32 + c) = o;
}

// ---------------- bf16 MFMA GEMM (64M x 128N, BK=128, swizzled LDS) ---------
// C[M=768][N] = A[768][K](bf16) * Wt[N][K](bf16)^T  (+bias)(+add f32)(relu)
// 256 threads = 4 waves (2Mx2N); per wave 32x64 output (acc 2x4 f32x4).
// BK=128, K=1024 -> 8 barrier-drain steps. LDS 48 KB -> 3 blocks/CU.
struct GemmOp {
  const unsigned short* A;
  const unsigned short* B;   // Wt, row n, col k, stride ldb
  const float* bias;         // [N] or null
  const float* add;          // [768][N] f32 or null
  float* Cf;                 // or null
  unsigned short* Cb;        // or null
  int lda, ldb, N, K, relu;
};
struct GemmBatch { GemmOp op[5]; };

__global__ __launch_bounds__(256, 3) void gemm_mfma(GemmBatch batch) {
  const GemmOp g = batch.op[blockIdx.z];
  __shared__ unsigned short As[64 * 128];    // [m][k] 16 KB, 256B rows
  __shared__ unsigned short Bs[128 * 128];   // [n][k] 32 KB
  const int bm = blockIdx.y * 64, bn = blockIdx.x * 128;
  const int tid = threadIdx.x;
  const int l = tid & 63, w = tid >> 6;
  const int wr = (w >> 1) * 32, wc = (w & 1) * 64;
  const int lr = l & 15, lg = l >> 4;
  const int crow = l >> 4;            // row within 4-row wave-chunk (0..3)
  const int c16 = l & 15;             // 16B slot within 256B row
  // LDS[row][cb] holds global[row][cb ^ ((row&7)<<4)]; row&7 = (ch&1)*4+crow.
  const int scolE = 8 * (c16 ^ crow);
  const int scolO = 8 * (c16 ^ (4 + crow));
  const char* AsB = (const char*)As;
  const char* BsB = (const char*)Bs;
  f32x4 acc[2][4] = {};
  for (int k0 = 0; k0 < g.K; k0 += 128) {
    __syncthreads();  // previous compute reads done
#pragma unroll
    for (int c = 0; c < 4; ++c) {           // A: 16 wave-chunks of 4 rows
      const int ch = w * 4 + c;
      const int sc = (ch & 1) ? scolO : scolE;
      gload16(g.A + (size_t)(bm + ch * 4 + crow) * g.lda + k0 + sc,
              &As[ch * 512 + l * 8]);
    }
#pragma unroll
    for (int c = 0; c < 8; ++c) {           // B: 32 wave-chunks of 4 rows
      const int ch = w * 8 + c;
      const int sc = (ch & 1) ? scolO : scolE;
      gload16(g.B + (size_t)(bn + ch * 4 + crow) * g.ldb + k0 + sc,
              &Bs[ch * 512 + l * 8]);
    }
    __syncthreads();  // compiler drains vmcnt(0) before barrier
#pragma unroll
    for (int ks = 0; ks < 4; ++ks) {
      short8 af[2], bf[4];
#pragma unroll
      for (int i = 0; i < 2; ++i) {
        const int ra = wr + i * 16 + lr;
        af[i] = *(const short8*)(AsB +
                 ((ra * 256 + ks * 64 + lg * 16) ^ ((ra & 7) << 4)));
      }
#pragma unroll
      for (int j = 0; j < 4; ++j) {
        const int rb = wc + j * 16 + lr;
        bf[j] = *(const short8*)(BsB +
                 ((rb * 256 + ks * 64 + lg * 16) ^ ((rb & 7) << 4)));
      }
#pragma unroll
      for (int i = 0; i < 2; ++i)
#pragma unroll
        for (int j = 0; j < 4; ++j)
          acc[i][j] =
              __builtin_amdgcn_mfma_f32_16x16x32_bf16(af[i], bf[j], acc[i][j], 0, 0, 0);
    }
  }
  // epilogue: C/D layout col=lane&15, row=(lane>>4)*4+reg
#pragma unroll
  for (int j = 0; j < 4; ++j) {
    const int col = bn + wc + j * 16 + lr;
    const float bv = g.bias ? g.bias[col] : 0.0f;
#pragma unroll
    for (int i = 0; i < 2; ++i) {
#pragma unroll
      for (int ii = 0; ii < 4; ++ii) {
        const int row = bm + wr + i * 16 + lg * 4 + ii;
        float v = acc[i][j][ii] + bv;
        if (g.add) v += g.add[(size_t)row * g.N + col];
        if (g.relu) v = fmaxf(v, 0.0f);
        if (g.Cf) g.Cf[(size_t)row * g.N + col] = v;
        if (g.Cb) g.Cb[(size_t)row * g.N + col] = f2bf(v);
      }
    }
  }
}

// ---------------- decision gate, pass 1 v3 ----------------------------------
__global__ __launch_bounds__(256) void decision_part(
    const float* __restrict__ A1, const float* __restrict__ A0,
    const float* __restrict__ w2, float* __restrict__ PART) {
  __shared__ float sA1[64][68];   // 64 rows x 64 d
  __shared__ float sA0[64][68];
  const int ds = blockIdx.x;      // d range [ds*64, ds*64+64)
  const int b = blockIdx.y, pp = blockIdx.z;
  const int i = pp / 3, j = pp % 3;
  const int tid = threadIdx.x;
  const int tq = tid >> 4, tk = tid & 15;
  const float* a1base = A1 + ((size_t)(j * 4 + b) * 64) * 2048 + ds * 64;
  const float* a0base = A0 + ((size_t)(i * 4 + b) * 64) * 2048 + ds * 64;
#pragma unroll
  for (int t = 0; t < 4; ++t) {
    const int row = t * 16 + tq;
    const int col = tk * 4;
    *(float4*)&sA1[row][col] = *(const float4*)(a1base + (size_t)row * 2048 + col);
    *(float4*)&sA0[row][col] = *(const float4*)(a0base + (size_t)row * 2048 + col);
  }
  __syncthreads();
  float acc[4][4] = {};
  const float* wbase = w2 + (size_t)ds * 128;
#pragma unroll 4
  for (int s4 = 0; s4 < 16; ++s4) {
    float4 wv0 = *(const float4*)(wbase + s4 * 8);
    float4 wv1 = *(const float4*)(wbase + s4 * 8 + 4);
    float wd0 = wv0.y - wv0.x, wd1 = wv0.w - wv0.z;
    float wd2 = wv1.y - wv1.x, wd3 = wv1.w - wv1.z;
    float4 a1v[4], a0v[4];
#pragma unroll
    for (int r = 0; r < 4; ++r) {
      a1v[r] = *(const float4*)&sA1[tq + 16 * r][s4 * 4];
      a0v[r] = *(const float4*)&sA0[tk + 16 * r][s4 * 4];
    }
#pragma unroll
    for (int qr = 0; qr < 4; ++qr)
#pragma unroll
      for (int kr = 0; kr < 4; ++kr) {
        float a = acc[qr][kr];
        a = fmaf(fmaxf(a1v[qr].x + a0v[kr].x, 0.f), wd0, a);
        a = fmaf(fmaxf(a1v[qr].y + a0v[kr].y, 0.f), wd1, a);
        a = fmaf(fmaxf(a1v[qr].z + a0v[kr].z, 0.f), wd2, a);
        a = fmaf(fmaxf(a1v[qr].w + a0v[kr].w, 0.f), wd3, a);
        acc[qr][kr] = a;
      }
  }
  float* outp = PART + (size_t)ds * 147456 + ((size_t)pp * 4 + b) * 4096;
#pragma unroll
  for (int qr = 0; qr < 4; ++qr)
#pragma unroll
    for (int kr = 0; kr < 4; ++kr)
      outp[(tq + 16 * qr) * 64 + (tk + 16 * kr)] = acc[qr][kr];
}

// ---------------- decision gate, pass 2: reduce + compare -------------------
__global__ __launch_bounds__(256) void decision_reduce(
    const float* __restrict__ PART, const float* __restrict__ b2,
    float* __restrict__ DEC) {
  const int out = blockIdx.x * 256 + threadIdx.x;
  float acc = 0.f;
#pragma unroll
  for (int s = 0; s < 32; ++s) acc += PART[(size_t)s * 147456 + out];
  const float thr = b2[0] - b2[1];
  DEC[out] = (acc > thr) ? NEGV : 0.f;
}

// ---------------- MFMA attention (full barrier discipline) ------------------
__global__ __launch_bounds__(256) void attn_mfma(
    const unsigned short* __restrict__ Qa, const unsigned short* __restrict__ Ka,
    const unsigned short* __restrict__ Va, const float* __restrict__ DEC,
    const int* __restrict__ mask, unsigned short* __restrict__ O) {
  __shared__ __align__(16) char sm[49408];
  char* KsP = sm;
  char* Vt = sm + 24576;
  float* invs = (float*)(sm + 49152);

  const int h = blockIdx.x, b = blockIdx.y, i = blockIdx.z;
  const int tid = threadIdx.x;
  const int l = tid & 63, w = tid >> 6;
  const int l15 = l & 15, lg = l >> 4;

#pragma unroll
  for (int rep = 0; rep < 6; ++rep) {
    int flat = rep * 256 + tid;
    int key = flat >> 3, c8 = flat & 7;
    int j = key >> 6, kl = key & 63;
    const size_t rowoff = (((size_t)(j * 4 + b) * 64 + kl) * 1024) + h * 64 + c8 * 8;
    u16x8 kv = *(const u16x8*)(Ka + rowoff);
    *(u16x8*)(KsP + ((key * 128 + c8 * 16) ^ ((key & 7) << 4))) = kv;
    u16x8 vv = *(const u16x8*)(Va + rowoff);
#pragma unroll
    for (int jj = 0; jj < 8; ++jj) {
      int d = c8 * 8 + jj;
      *(unsigned short*)(Vt + ((d * 384 + key * 2) ^ ((d & 7) << 4))) = vv[jj];
    }
  }

  const int qg = w * 16 + l15;
  const unsigned short* qsrc =
      Qa + (((size_t)(i * 4 + b) * 64 + qg) * 1024) + h * 64 + lg * 8;
  short8 qf0 = *(const short8*)(qsrc);
  short8 qf1 = *(const short8*)(qsrc + 32);

  __syncthreads();  // (1)

  f32x4 s[12];
#pragma unroll
  for (int t = 0; t < 12; ++t) {
    const int key = t * 16 + l15;
    const int swz = (key & 7) << 4;
    short8 kf0 = *(const short8*)(KsP + ((key * 128 + 0 + lg * 16) ^ swz));
    short8 kf1 = *(const short8*)(KsP + ((key * 128 + 64 + lg * 16) ^ swz));
    f32x4 z = {0.f, 0.f, 0.f, 0.f};
    z = __builtin_amdgcn_mfma_f32_16x16x32_bf16(kf0, qf0, z, 0, 0, 0);
    z = __builtin_amdgcn_mfma_f32_16x16x32_bf16(kf1, qf1, z, 0, 0, 0);
    s[t] = z;
  }

  int mk[4][4];
#pragma unroll
  for (int t4 = 0; t4 < 4; ++t4)
#pragma unroll
    for (int r = 0; r < 4; ++r)
      mk[t4][r] = mask[((size_t)b * 64 + qg) * 64 + t4 * 16 + lg * 4 + r];

  float mx = -3.0e38f;
#pragma unroll
  for (int t = 0; t < 12; ++t) {
    const float* dbase =
        DEC + (((size_t)(i * 3 + (t >> 2)) * 4 + b) * 4096) + qg * 64;
#pragma unroll
    for (int r = 0; r < 4; ++r) {
      const int kl = (t & 3) * 16 + lg * 4 + r;
      float sv = s[t][r] * 0.125f + dbase[kl];
      if (mk[t & 3][r] == 0) sv = NEGV;
      s[t][r] = sv;
      mx = fmaxf(mx, sv);
    }
  }
  mx = fmaxf(mx, __shfl_xor(mx, 16));
  mx = fmaxf(mx, __shfl_xor(mx, 32));
  float sum = 0.f;
#pragma unroll
  for (int t = 0; t < 12; ++t)
#pragma unroll
    for (int r = 0; r < 4; ++r) {
      float p = __expf(s[t][r] - mx);
      s[t][r] = p;
      sum += p;
    }
  sum += __shfl_xor(sum, 16);
  sum += __shfl_xor(sum, 32);
  if (l < 16) invs[w * 16 + l] = 1.0f / sum;

  __syncthreads();  // (2)

  char* Pmy = KsP + w * 6144;
  const int pswz = (l15 & 7) << 4;

#pragma unroll
  for (int t = 0; t < 12; ++t)
#pragma unroll
    for (int r = 0; r < 4; ++r) {
      const int key = t * 16 + lg * 4 + r;
      *(unsigned short*)(Pmy + ((l15 * 384 + key * 2) ^ pswz)) = f2bf(s[t][r]);
    }
  __syncthreads();  // (3)

  f32x4 o[4] = {};
#pragma unroll
  for (int kc = 0; kc < 6; ++kc) {
    short8 pf = *(const short8*)(Pmy + ((l15 * 384 + kc * 64 + lg * 16) ^ pswz));
#pragma unroll
    for (int dt = 0; dt < 4; ++dt) {
      const int d = dt * 16 + l15;
      short8 vf = *(const short8*)(Vt + ((d * 384 + kc * 64 + lg * 16) ^ ((d & 7) << 4)));
      o[dt] = __builtin_amdgcn_mfma_f32_16x16x32_bf16(pf, vf, o[dt], 0, 0, 0);
    }
  }
  __syncthreads();  // (4)

#pragma unroll
  for (int t = 0; t < 12; ++t)
#pragma unroll
    for (int r = 0; r < 4; ++r) {
      const int key = t * 16 + lg * 4 + r;
      float p = s[t][r];
      float lo = p - bf2f(f2bf(p));
      *(unsigned short*)(Pmy + ((l15 * 384 + key * 2) ^ pswz)) = f2bf(lo);
    }
  __syncthreads();  // (5)

#pragma unroll
  for (int kc = 0; kc < 6; ++kc) {
    short8 pf = *(const short8*)(Pmy + ((l15 * 384 + kc * 64 + lg * 16) ^ pswz));
#pragma unroll
    for (int dt = 0; dt < 4; ++dt) {
      const int d = dt * 16 + l15;
      short8 vf = *(const short8*)(Vt + ((d * 384 + kc * 64 + lg * 16) ^ ((d & 7) << 4)));
      o[dt] = __builtin_amdgcn_mfma_f32_16x16x32_bf16(pf, vf, o[dt], 0, 0, 0);
    }
  }

#pragma unroll
  for (int dt = 0; dt < 4; ++dt)
#pragma unroll
    for (int r = 0; r < 4; ++r) {
      const int ql = lg * 4 + r;
      const float inv = invs[w * 16 + ql];
      const int d = dt * 16 + l15;
      O[(((size_t)(i * 4 + b) * 64 + w * 16 + ql) * 1024) + h * 64 + d] =
          f2bf(o[dt][r] * inv);
    }
}

// ---------------- generic fused k-split reduce + layer norm -----------------
// v = fixed-order sum of nparts partials (stride 786432) [+bias] + add; LN;
// writes Yf (f32) and optionally Yb (bf16).
__global__ __launch_bounds__(256) void fsum_ln(
    const float* __restrict__ P, int nparts, const float* __restrict__ bias,
    const float* __restrict__ add, const float* __restrict__ g,
    const float* __restrict__ be, float* __restrict__ Yf,
    unsigned short* __restrict__ Yb) {
  __shared__ float rs[8];
  int row = blockIdx.x, tid = threadIdx.x;
  const int c = tid * 4;
  const size_t o = (size_t)row * 1024 + c;
  float4 v;
  if (nparts == 4) {
    float4 p0 = *(const float4*)(P + o);
    float4 p1 = *(const float4*)(P + 786432 + o);
    float4 p2 = *(const float4*)(P + 2 * 786432 + o);
    float4 p3 = *(const float4*)(P + 3 * 786432 + o);
    v.x = (p0.x + p1.x) + (p2.x + p3.x);
    v.y = (p0.y + p1.y) + (p2.y + p3.y);
    v.z = (p0.z + p1.z) + (p2.z + p3.z);
    v.w = (p0.w + p1.w) + (p2.w + p3.w);
  } else {
    float4 p0 = *(const float4*)(P + o);
    float4 p1 = *(const float4*)(P + 786432 + o);
    v.x = p0.x + p1.x; v.y = p0.y + p1.y;
    v.z = p0.z + p1.z; v.w = p0.w + p1.w;
  }
  if (bias) {
    float4 bs = *(const float4*)(bias + c);
    v.x += bs.x; v.y += bs.y; v.z += bs.z; v.w += bs.w;
  }
  float4 ad = *(const float4*)(add + o);
  v.x += ad.x; v.y += ad.y; v.z += ad.z; v.w += ad.w;
  float s = v.x + v.y + v.z + v.w;
  float s2 = v.x * v.x + v.y * v.y + v.z * v.z + v.w * v.w;
#pragma unroll
  for (int off = 32; off > 0; off >>= 1) {
    s += __shfl_down(s, off);
    s2 += __shfl_down(s2, off);
  }
  int lane = tid & 63, wid = tid >> 6;
  if (lane == 0) { rs[wid * 2] = s; rs[wid * 2 + 1] = s2; }
  __syncthreads();
  if (tid == 0) {
    float aa = rs[0] + rs[2] + rs[4] + rs[6];
    float cc = rs[1] + rs[3] + rs[5] + rs[7];
    rs[0] = aa; rs[1] = cc;
  }
  __syncthreads();
  float mu = rs[0] * (1.0f / 1024.0f);
  float var = rs[1] * (1.0f / 1024.0f) - mu * mu;
  var = fmaxf(var, 0.f);
  float inv = 1.0f / sqrtf(var + 1e-6f);
  float4 gv = *(const float4*)(g + c);
  float4 bv = *(const float4*)(be + c);
  float4 r;
  r.x = (v.x - mu) * inv * gv.x + bv.x;
  r.y = (v.y - mu) * inv * gv.y + bv.y;
  r.z = (v.z - mu) * inv * gv.z + bv.z;
  r.w = (v.w - mu) * inv * gv.w + bv.w;
  *(float4*)(Yf + o) = r;
  if (Yb) {
    u16x4 ob;
    ob.x = f2bf(r.x); ob.y = f2bf(r.y); ob.z = f2bf(r.z); ob.w = f2bf(r.w);
    *(u16x4*)(Yb + o) = ob;
  }
}

// ---------------------------------------------------------------------------
extern "C" void kernel_launch(void* const* d_in, const int* in_sizes, int n_in,
                              void* d_out, int out_size, void* d_ws,
                              size_t ws_size, hipStream_t stream) {
  const float* in_t = (const float*)d_in[0];
  const float* in_a = (const float*)d_in[1];
  const float* in_v = (const float*)d_in[2];
  const int* mask = (const int*)d_in[3];
  const float* w_qs = (const float*)d_in[4];
  const float* w_ks = (const float*)d_in[5];
  const float* w_vs = (const float*)d_in[6];
  const float* w_ds0 = (const float*)d_in[7];
  const float* w_ds1 = (const float*)d_in[8];
  const float* dc_w1 = (const float*)d_in[9];
  const float* dc_b1 = (const float*)d_in[10];
  const float* dc_w2 = (const float*)d_in[11];
  const float* dc_b2 = (const float*)d_in[12];
  const float* w_fc = (const float*)d_in[13];
  const float* ln1_g = (const float*)d_in[14];
  const float* ln1_b = (const float*)d_in[15];
  const float* ffn_w1 = (const float*)d_in[16];
  const float* ffn_b1 = (const float*)d_in[17];
  const float* ffn_w2 = (const float*)d_in[18];
  const float* ffn_b2 = (const float*)d_in[19];
  const float* ln2_g = (const float*)d_in[20];
  const float* ln2_b = (const float*)d_in[21];
  float* out = (float*)d_out;

  char* p = (char*)d_ws;
  auto alloc = [&](size_t bytes) {
    char* r = p;
    p += (bytes + 255) & ~(size_t)255;
    return r;
  };
  unsigned short* WQS = (unsigned short*)alloc(1024 * 1024 * 2);
  unsigned short* WKS = (unsigned short*)alloc(1024 * 1024 * 2);
  unsigned short* WVS = (unsigned short*)alloc(1024 * 1024 * 2);
  unsigned short* WD0 = (unsigned short*)alloc(1024 * 1024 * 2);
  unsigned short* WD1 = (unsigned short*)alloc(1024 * 1024 * 2);
  unsigned short* WW1 = (unsigned short*)alloc((size_t)2048 * 2048 * 2);
  unsigned short* WFC = (unsigned short*)alloc(1024 * 1024 * 2);
  unsigned short* WF1 = (unsigned short*)alloc((size_t)4096 * 1024 * 2);
  unsigned short* WF2 = (unsigned short*)alloc((size_t)1024 * 4096 * 2);
  float* Xf = (float*)alloc((size_t)786432 * 4);
  unsigned short* Xb = (unsigned short*)alloc((size_t)786432 * 2);
  unsigned short* Qb = (unsigned short*)alloc((size_t)786432 * 2);
  unsigned short* Kb = (unsigned short*)alloc((size_t)786432 * 2);
  unsigned short* Vb = (unsigned short*)alloc((size_t)786432 * 2);
  unsigned short* D0b = (unsigned short*)alloc((size_t)786432 * 2);
  unsigned short* D1b = (unsigned short*)alloc((size_t)786432 * 2);
  float* DEC = (float*)alloc((size_t)147456 * 4);
  unsigned short* OATTb = (unsigned short*)alloc((size_t)786432 * 2);
  float* PART = (float*)alloc((size_t)32 * 147456 * 4);  // 18.9 MB partials
  float* FPART = PART;  // reused after decision for fc / ffn2 k-splits
  char* U = alloc((size_t)14155776);
  float* A0f = (float*)U;
  float* A1f = (float*)(U + (size_t)6291456);
  float* O1f = (float*)(U + (size_t)3145728);
  unsigned short* O1b = (unsigned short*)(U + (size_t)6291456);
  unsigned short* Hfb = (unsigned short*)(U + (size_t)7864320);

  dim3 blk(256);

  WtJobs jobs;
  int ts = 0;
  auto setjob = [&](int idx, const float* s, unsigned short* d, int K, int N) {
    jobs.j[idx].src = s; jobs.j[idx].dst = d;
    jobs.j[idx].K = K; jobs.j[idx].N = N; jobs.j[idx].tstart = ts;
    ts += (K / 32) * (N / 32);
  };
  setjob(0, w_qs, WQS, 1024, 1024);
  setjob(1, w_ks, WKS, 1024, 1024);
  setjob(2, w_vs, WVS, 1024, 1024);
  setjob(3, w_ds0, WD0, 1024, 1024);
  setjob(4, w_ds1, WD1, 1024, 1024);
  setjob(5, dc_w1, WW1, 2048, 2048);
  setjob(6, w_fc, WFC, 1024, 1024);
  setjob(7, ffn_w1, WF1, 1024, 4096);
  setjob(8, ffn_w2, WF2, 4096, 1024);
  prep<<<dim3(768 + ts), blk, 0, stream>>>((const float4*)in_t,
                                           (const float4*)in_a,
                                           (const float4*)in_v,
                                           (float4*)Xf, (u16x4*)Xb, jobs);

  GemmBatch proj{};
  unsigned short* pouts[5] = {Qb, Kb, Vb, D0b, D1b};
  const unsigned short* pws[5] = {WQS, WKS, WVS, WD0, WD1};
  for (int z = 0; z < 5; ++z) {
    proj.op[z].A = Xb; proj.op[z].B = pws[z];
    proj.op[z].bias = nullptr; proj.op[z].add = nullptr;
    proj.op[z].Cf = nullptr; proj.op[z].Cb = pouts[z];
    proj.op[z].lda = 1024; proj.op[z].ldb = 1024;
    proj.op[z].N = 1024; proj.op[z].K = 1024; proj.op[z].relu = 0;
  }
  gemm_mfma<<<dim3(8, 12, 5), blk, 0, stream>>>(proj);

  GemmBatch pair{};
  pair.op[0].A = D0b; pair.op[0].B = WW1 + 1024;
  pair.op[0].bias = nullptr; pair.op[0].add = nullptr;
  pair.op[0].Cf = A0f; pair.op[0].Cb = nullptr;
  pair.op[0].lda = 1024; pair.op[0].ldb = 2048;
  pair.op[0].N = 2048; pair.op[0].K = 1024; pair.op[0].relu = 0;
  pair.op[1] = pair.op[0];
  pair.op[1].A = D1b; pair.op[1].B = WW1; pair.op[1].bias = dc_b1;
  pair.op[1].Cf = A1f;
  gemm_mfma<<<dim3(16, 12, 2), blk, 0, stream>>>(pair);

  decision_part<<<dim3(32, 4, 9), blk, 0, stream>>>(A1f, A0f, dc_w2, PART);
  decision_reduce<<<dim3(576), blk, 0, stream>>>(PART, dc_b2, DEC);

  attn_mfma<<<dim3(16, 4, 3), blk, 0, stream>>>(Qb, Kb, Vb, DEC, mask, OATTb);

  // fc k-split x2: partials into FPART, then fused reduce + residual + LN1
  GemmBatch fc{};
  for (int z = 0; z < 2; ++z) {
    fc.op[z].A = OATTb + (size_t)z * 512;
    fc.op[z].B = WFC + (size_t)z * 512;
    fc.op[z].bias = nullptr; fc.op[z].add = nullptr;
    fc.op[z].Cf = FPART + (size_t)z * 786432; fc.op[z].Cb = nullptr;
    fc.op[z].lda = 1024; fc.op[z].ldb = 1024;
    fc.op[z].N = 1024; fc.op[z].K = 512; fc.op[z].relu = 0;
  }
  gemm_mfma<<<dim3(8, 12, 2), blk, 0, stream>>>(fc);
  fsum_ln<<<dim3(768), blk, 0, stream>>>(FPART, 2, nullptr, Xf, ln1_g, ln1_b,
                                         O1f, O1b);

  GemmBatch f1{};
  f1.op[0].A = O1b; f1.op[0].B = WF1;
  f1.op[0].bias = ffn_b1; f1.op[0].add = nullptr;
  f1.op[0].Cf = nullptr; f1.op[0].Cb = Hfb;
  f1.op[0].lda = 1024; f1.op[0].ldb = 1024;
  f1.op[0].N = 4096; f1.op[0].K = 1024; f1.op[0].relu = 1;
  gemm_mfma<<<dim3(32, 12, 1), blk, 0, stream>>>(f1);

  // FFN2 k-split x4: partials into FPART, then fused reduce+LN2
  GemmBatch f2{};
  for (int z = 0; z < 4; ++z) {
    f2.op[z].A = Hfb + (size_t)z * 1024;
    f2.op[z].B = WF2 + (size_t)z * 1024;
    f2.op[z].bias = nullptr; f2.op[z].add = nullptr;
    f2.op[z].Cf = FPART + (size_t)z * 786432; f2.op[z].Cb = nullptr;
    f2.op[z].lda = 4096; f2.op[z].ldb = 4096;
    f2.op[z].N = 1024; f2.op[z].K = 1024; f2.op[z].relu = 0;
  }
  gemm_mfma<<<dim3(8, 12, 4), blk, 0, stream>>>(f2);

  fsum_ln<<<dim3(768), blk, 0, stream>>>(FPART, 4, ffn_b2, O1f, ln2_g, ln2_b,
                                         out, nullptr);
}